// Round 4
// baseline (971.501 us; speedup 1.0000x reference)
//
#include <hip/hip_runtime.h>

// ---------------------------------------------------------------------------
// TPUGEMMLinear: blockwise-fp8 quantize (block=128) of x[M,K] (along K) and
// w[K,N] (along N), dequant-scaled fp32 GEMM + bias.
// R4: deepen vmcnt coverage in the gemm. R3 measured bank-conflict=0 but
// MfmaUtil only 47.6% — the residual stall is vmcnt waits with only 2-3
// phases of issue->wait distance (p8 awaited a load issued at p6). New
// staging schedule issues each half-tile as early as WAR allows:
//   p3: Ah0(T+2)          p4: Ah1+Bh0+Bh1(T+2), WAITV(8)
//   p7: Ah0+Ah1(T+3)      p8: Bh0+Bh1(T+3),     WAITV(8)
// -> uniform 4-phase (~600 cyc) coverage, symmetric WAITV(8) ledger.
// Quant kernels unchanged (controlled A/B; residual-vs-gemm attribution).
// Swizzle (from R3, verified conflict-free): LDS byte = row*128 +
// (col ^ ((row&7)<<4)); write side pre-swizzles the per-lane global column
// (linear global_load_lds dest); read side applies the same XOR.
// Workspace: Xd bf16 [M*K] | Bt bf16 [N*K]  (160 MB).
// ---------------------------------------------------------------------------

typedef __attribute__((ext_vector_type(8))) short short8;   // 8 x bf16 frag
typedef __attribute__((ext_vector_type(4))) float f32x4;
typedef unsigned short ushort_t;

__device__ __forceinline__ float fp8_round_trip(float v) {
    int p = __builtin_amdgcn_cvt_pk_fp8_f32(v, v, 0, false);
    return __builtin_amdgcn_cvt_f32_fp8(p, 0);
}

__device__ __forceinline__ ushort_t f32_to_bf16(float f) {
    union { float f; unsigned u; } un; un.f = f;
    unsigned r = un.u + 0x7fffu + ((un.u >> 16) & 1u);
    return (ushort_t)(r >> 16);
}

// async 16B/lane global -> LDS (wave-uniform LDS base + lane*16)
__device__ __forceinline__ void async16(const void* g, void* l) {
    __builtin_amdgcn_global_load_lds(
        (const __attribute__((address_space(1))) unsigned int*)g,
        (__attribute__((address_space(3))) unsigned int*)l,
        16, 0, 0);
}

// ---------------------------------------------------------------------------
// quant_x v2: x[M,K] f32 -> Xd[M,K] bf16 (dequantized). Each wave handles
// 512 consecutive elems as two coalesced float4 streams; each 32-lane
// half-wave owns one 128-elem fp8 block per stream.
// ---------------------------------------------------------------------------
__global__ __launch_bounds__(256) void quant_x_kernel(
        const float* __restrict__ x, ushort_t* __restrict__ xd) {
    size_t tid  = (size_t)blockIdx.x * 256 + threadIdx.x;
    int lane = threadIdx.x & 63;
    size_t wbase = (tid >> 6) * 512;
    size_t i0 = wbase + (size_t)lane * 4;
    size_t i1 = i0 + 256;
    float4 v0 = *(const float4*)(x + i0);
    float4 v1 = *(const float4*)(x + i1);
    float a0 = fmaxf(fmaxf(fabsf(v0.x), fabsf(v0.y)),
                     fmaxf(fabsf(v0.z), fabsf(v0.w)));
    float a1 = fmaxf(fmaxf(fabsf(v1.x), fabsf(v1.y)),
                     fmaxf(fabsf(v1.z), fabsf(v1.w)));
    #pragma unroll
    for (int m = 1; m < 32; m <<= 1) {
        a0 = fmaxf(a0, __shfl_xor(a0, m, 64));
        a1 = fmaxf(a1, __shfl_xor(a1, m, 64));
    }
    float s0 = fmaxf(a0 / 448.0f, 1e-12f);
    float s1 = fmaxf(a1 / 448.0f, 1e-12f);
    ushort4 o0, o1;
    o0.x = f32_to_bf16(fp8_round_trip(v0.x / s0) * s0);
    o0.y = f32_to_bf16(fp8_round_trip(v0.y / s0) * s0);
    o0.z = f32_to_bf16(fp8_round_trip(v0.z / s0) * s0);
    o0.w = f32_to_bf16(fp8_round_trip(v0.w / s0) * s0);
    o1.x = f32_to_bf16(fp8_round_trip(v1.x / s1) * s1);
    o1.y = f32_to_bf16(fp8_round_trip(v1.y / s1) * s1);
    o1.z = f32_to_bf16(fp8_round_trip(v1.z / s1) * s1);
    o1.w = f32_to_bf16(fp8_round_trip(v1.w / s1) * s1);
    *(ushort4*)(xd + i0) = o0;
    *(ushort4*)(xd + i1) = o1;
}

// ---------------------------------------------------------------------------
// quant_w: w[K,N] f32 -> Bt[N,K] bf16 (dequantized + transposed). Unchanged.
// ---------------------------------------------------------------------------
__global__ __launch_bounds__(256) void quant_w_kernel(
        const float* __restrict__ w, ushort_t* __restrict__ bt,
        int K, int N) {
    __shared__ float lds[128 * 65];
    int k0 = blockIdx.x * 64;
    int n0 = blockIdx.y * 128;
    int t = threadIdx.x;
    int wid = t >> 6, lane = t & 63;
    int half = lane >> 5, l32 = lane & 31;

    #pragma unroll
    for (int rr = 0; rr < 8; ++rr) {
        int klocal = wid * 16 + rr * 2 + half;
        int k = k0 + klocal;
        float4 v = *(const float4*)(w + (size_t)k * N + n0 + l32 * 4);
        float amax = fmaxf(fmaxf(fabsf(v.x), fabsf(v.y)),
                           fmaxf(fabsf(v.z), fabsf(v.w)));
        #pragma unroll
        for (int m = 1; m < 32; m <<= 1)
            amax = fmaxf(amax, __shfl_xor(amax, m, 64));
        float scale = fmaxf(amax / 448.0f, 1e-12f);
        int nl = l32 * 4;
        lds[(nl + 0) * 65 + klocal] = fp8_round_trip(v.x / scale) * scale;
        lds[(nl + 1) * 65 + klocal] = fp8_round_trip(v.y / scale) * scale;
        lds[(nl + 2) * 65 + klocal] = fp8_round_trip(v.z / scale) * scale;
        lds[(nl + 3) * 65 + klocal] = fp8_round_trip(v.w / scale) * scale;
    }
    __syncthreads();
    #pragma unroll
    for (int it = 0; it < 8; ++it) {
        int idx = it * 256 + t;
        int j = idx >> 4;
        int c = idx & 15;
        const float* p = &lds[j * 65 + c * 4];
        ushort4 o;
        o.x = f32_to_bf16(p[0]);
        o.y = f32_to_bf16(p[1]);
        o.z = f32_to_bf16(p[2]);
        o.w = f32_to_bf16(p[3]);
        *(ushort4*)(bt + (size_t)(n0 + j) * K + k0 + c * 4) = o;
    }
}

// ---------------------------------------------------------------------------
// gemm256: C[M,N] = A[M,K](bf16) * Bt[N,K](bf16)^T + bias.
// 256x256 tile, BK=64, 512 threads = 8 waves (wr in {0,1} x wcn in {0..3});
// per-wave output 128x64 = acc[8][4] f32x4. LDS dbuf 128 KiB.
//
// Phase schedule per iteration (2 K-tiles: T=2i in buf0, T+1 in buf1):
//  p1: read B01+A0(T)   [12 ds]                          | Q0 acc[0-3][0-1]
//  p2: read A1(T)       [ 8 ds]                          | Q1 acc[4-7][0-1]
//  p3: read B23(T)      [ 4 ds] | stage Ah0(T+2)->buf0   | Q2 acc[0-3][2-3]
//  p4:  stage Ah1+Bh0+Bh1(T+2)->buf0, WAITV(8)           | Q3 acc[4-7][2-3]
//  p5: read B01+A0(T+1) [12 ds]                          | Q0
//  p6: read A1(T+1)     [ 8 ds]                          | Q1
//  p7: read B23(T+1)    [ 4 ds] | stage Ah0+Ah1(T+3)->buf1 | Q2
//  p8:  stage Bh0+Bh1(T+3)->buf1, WAITV(8)               | Q3
// WAR: buf0 A-slots free after p2, B-slots after p3; buf1 A after p6,
// B after p7 — every stage above sits >= one trailing barrier later.
// Ledger (2 loads/half): enter iter with 8 outstanding (tile T+1, issued
// p7/p8 of prev iter); +2@p3, +6@p4 -> WAITV(8) completes T+1 (4-phase
// coverage); +4@p7, +4@p8 -> WAITV(8) completes T+2 (4-phase coverage).
// ---------------------------------------------------------------------------

#define GBAR()    asm volatile("s_barrier" ::: "memory")
#define WAITL(n)  asm volatile("s_waitcnt lgkmcnt(" #n ")" ::: "memory")
#define WAITV(n)  asm volatile("s_waitcnt vmcnt(" #n ")" ::: "memory")

#define STAGE_A(h, kt, buf) do {                                             \
    const ushort_t* g_ = aSrc + (size_t)((h) * 128) * K + (size_t)(kt) * 64; \
    ushort_t* l_ = &sm[buf][0][(h) * 8192] + wid * 512;                      \
    async16(g_, l_);                                                         \
    async16(g_ + (size_t)64 * K, l_ + 4096);                                 \
} while (0)

#define STAGE_B(h, kt, buf) do {                                             \
    const ushort_t* g_ = bSrc + (size_t)((h) * 128) * K + (size_t)(kt) * 64; \
    ushort_t* l_ = &sm[buf][1][(h) * 8192] + wid * 512;                      \
    async16(g_, l_);                                                         \
    async16(g_ + (size_t)64 * K, l_ + 4096);                                 \
} while (0)

// A frags: dst[m][ks] = rows wr*128 + hsel*64 + m*16 + l16, k-slice cs0/cs1
#define LDA_(dst, buf, hsel) do {                                            \
    const char* p_ = smA[buf] + aBase + (hsel) * 8192;                       \
    _Pragma("unroll") for (int m_ = 0; m_ < 4; ++m_) {                       \
        dst[m_][0] = *(const short8*)(p_ + m_ * 2048 + cs0);                 \
        dst[m_][1] = *(const short8*)(p_ + m_ * 2048 + cs1);                 \
    }                                                                        \
} while (0)

// B frags: bb[n][ks] = rows wcn*64 + nsel*32 + n*16 + l16
#define LDB_(buf, nsel) do {                                                 \
    const char* p_ = smB[buf] + bBase + (nsel) * 4096;                       \
    _Pragma("unroll") for (int n_ = 0; n_ < 2; ++n_) {                       \
        bb[n_][0] = *(const short8*)(p_ + n_ * 2048 + cs0);                  \
        bb[n_][1] = *(const short8*)(p_ + n_ * 2048 + cs1);                  \
    }                                                                        \
} while (0)

#define MFMAQ(AS, mb, nb) do {                                               \
    _Pragma("unroll") for (int m_ = 0; m_ < 4; ++m_)                         \
    _Pragma("unroll") for (int n_ = 0; n_ < 2; ++n_) {                       \
        acc[(mb) + m_][(nb) + n_] = __builtin_amdgcn_mfma_f32_16x16x32_bf16( \
            AS[m_][0], bb[n_][0], acc[(mb) + m_][(nb) + n_], 0, 0, 0);       \
        acc[(mb) + m_][(nb) + n_] = __builtin_amdgcn_mfma_f32_16x16x32_bf16( \
            AS[m_][1], bb[n_][1], acc[(mb) + m_][(nb) + n_], 0, 0, 0);       \
    }                                                                        \
} while (0)

#define PH_TOP()  GBAR(); WAITL(0); __builtin_amdgcn_sched_barrier(0);       \
                  __builtin_amdgcn_s_setprio(1)
#define PH_END()  __builtin_amdgcn_s_setprio(0); GBAR()

__global__ __launch_bounds__(512, 2) void gemm256_kernel(
        const ushort_t* __restrict__ A, const ushort_t* __restrict__ B,
        const float* __restrict__ bias, float* __restrict__ C,
        int M, int N, int K) {
    __shared__ ushort_t sm[2][2][16384];   // 128 KiB

    const int t = threadIdx.x;
    const int wid = t >> 6;
    const int lane = t & 63;
    const int quad = lane >> 4, l16 = lane & 15;
    const int wr = wid >> 2, wcn = wid & 3;

    // T1: XCD-aware swizzle on flattened block id (nwg = 1024, % 8 == 0)
    const int nwg = gridDim.x;
    const int bid = blockIdx.x;
    int wg = bid;
    if ((nwg & 7) == 0) { const int cpx = nwg >> 3; wg = (bid & 7) * cpx + (bid >> 3); }
    const int nbn = N >> 8;
    const int bm = wg / nbn, bn = wg % nbn;

    // staging: thread t covers LDS linear byte t*16 per 64-row statement:
    // row = t>>3, col = (t&7)*16. Pre-swizzled global col = col ^ ((row&7)<<4).
    const int srow = t >> 3;
    const int scol = ((((t & 7) * 16) ^ (((t >> 3) & 7) << 4)) >> 1); // ushorts
    const ushort_t* aSrc = A + (size_t)(bm * 256 + srow) * K + scol;
    const ushort_t* bSrc = B + (size_t)(bn * 256 + srow) * K + scol;

    // ds_read addressing: row base l16*128; k-slice cols XOR-swizzled by row
    const int xr4 = (l16 & 7) << 4;
    const int cs0 = (quad * 16) ^ xr4;
    const int cs1 = (quad * 16 + 64) ^ xr4;
    const int aBase = wr * 16384 + l16 * 128;    // bytes within A tile
    const int bBase = wcn * 8192 + l16 * 128;    // bytes within B tile
    const char* smA[2] = { (const char*)sm[0][0], (const char*)sm[1][0] };
    const char* smB[2] = { (const char*)sm[0][1], (const char*)sm[1][1] };

    f32x4 acc[8][4] = {};
    short8 a0[4][2], a1[4][2], bb[2][2];

    const int NT = K >> 6;     // K-tiles (64)
    const int NI = NT >> 1;    // iterations (32)

    // prologue: tile0 (8 loads) + tile1 (8 loads); drain tile0, keep 8.
    STAGE_A(0, 0, 0); STAGE_A(1, 0, 0); STAGE_B(0, 0, 0); STAGE_B(1, 0, 0);
    STAGE_A(0, 1, 1); STAGE_A(1, 1, 1); STAGE_B(0, 1, 1); STAGE_B(1, 1, 1);
    WAITV(8); GBAR();

    for (int i = 0; i < NI; ++i) {
        const int T  = 2 * i;
        const int t2 = (T + 2 < NT) ? T + 2 : 0;   // clamped: re-stages tile0,
        const int t3 = (T + 3 < NT) ? T + 3 : 0;   // never computed

        // ---- phase 1
        LDB_(0, 0); LDA_(a0, 0, 0);
        WAITL(8);
        PH_TOP(); MFMAQ(a0, 0, 0); PH_END();
        // ---- phase 2
        LDA_(a1, 0, 1);
        PH_TOP(); MFMAQ(a1, 4, 0); PH_END();
        // ---- phase 3
        LDB_(0, 1);
        STAGE_A(0, t2, 0);
        PH_TOP(); MFMAQ(a0, 0, 2); PH_END();
        // ---- phase 4
        STAGE_A(1, t2, 0);
        STAGE_B(0, t2, 0);
        STAGE_B(1, t2, 0);
        WAITV(8);
        GBAR(); __builtin_amdgcn_s_setprio(1); MFMAQ(a1, 4, 2); PH_END();
        // ---- phase 5
        LDB_(1, 0); LDA_(a0, 1, 0);
        WAITL(8);
        PH_TOP(); MFMAQ(a0, 0, 0); PH_END();
        // ---- phase 6
        LDA_(a1, 1, 1);
        PH_TOP(); MFMAQ(a1, 4, 0); PH_END();
        // ---- phase 7
        LDB_(1, 1);
        STAGE_A(0, t3, 1);
        STAGE_A(1, t3, 1);
        PH_TOP(); MFMAQ(a0, 0, 2); PH_END();
        // ---- phase 8
        STAGE_B(0, t3, 1);
        STAGE_B(1, t3, 1);
        WAITV(8);
        GBAR(); __builtin_amdgcn_s_setprio(1); MFMAQ(a1, 4, 2); PH_END();
    }

    // epilogue: C/D layout col = lane&15, row = quad*4 + reg (m89/m91)
    #pragma unroll
    for (int nt = 0; nt < 4; ++nt) {
        const int col = bn * 256 + wcn * 64 + nt * 16 + l16;
        const float bv = bias[col];
        #pragma unroll
        for (int mt = 0; mt < 8; ++mt) {
            const int row0 = bm * 256 + wr * 128 + mt * 16 + quad * 4;
            #pragma unroll
            for (int r = 0; r < 4; ++r)
                C[(size_t)(row0 + r) * N + col] = acc[mt][nt][r] + bv;
        }
    }
}

// ---------------------------------------------------------------------------
extern "C" void kernel_launch(void* const* d_in, const int* in_sizes, int n_in,
                              void* d_out, int out_size, void* d_ws, size_t ws_size,
                              hipStream_t stream) {
    const float* x    = (const float*)d_in[0];
    const float* w    = (const float*)d_in[1];
    const float* bias = (const float*)d_in[2];
    float* out = (float*)d_out;

    const int N = in_sizes[2];              // 4096
    const int K = in_sizes[1] / N;          // 4096
    const int M = in_sizes[0] / K;          // 16384

    ushort_t* xd = (ushort_t*)d_ws;                  // M*K bf16
    ushort_t* bt = xd + (size_t)M * K;               // N*K bf16
    // requires ws_size >= (M*K + N*K)*2 = 160 MB

    quant_x_kernel<<<(size_t)M * K / 2048, 256, 0, stream>>>(x, xd);
    quant_w_kernel<<<dim3(K / 64, N / 128), 256, 0, stream>>>(w, bt, K, N);
    gemm256_kernel<<<dim3((M / 256) * (N / 256)), 512, 0, stream>>>(
        xd, bt, bias, out, M, N, K);
}

// Round 5
// 905.175 us; speedup vs baseline: 1.0733x; 1.0733x over previous
//
#include <hip/hip_runtime.h>

// ---------------------------------------------------------------------------
// TPUGEMMLinear: blockwise-fp8 quantize (block=128) of x[M,K] (along K) and
// w[K,N] (along N), dequant-scaled fp32 GEMM + bias.
// R5: intra-phase LDS/MFMA overlap. R3/R4 measured MfmaUtil 43-47% ==
// the zero-overlap prediction (MFMA 1229 cyc vs LDS-read 1536 cyc per iter
// per CU, serialized by the lgkmcnt(0)-then-MFMA phase shape). Fix: pin
// ds_read issue order with asm volatile ds_read_b128, then a graduated
// lgkm ladder (DS returns are in-order): WAITL(4)->MFMA m0/m1 groups while
// m2/m3 reads are in flight -> WAITL(0)->finish. sched_barrier(0) after
// every waitcnt (rule #18). Staging schedule reverted to R3's measured-best
// placement (WAITV(4)@p4, WAITV(6)@p8, stages staggered p1/p3/p4/p5/p6/p7/p8).
// quant_x reverted to v1 (v2 cost ~+35us residual).
// Swizzle (R3, verified 0-conflict): LDS byte = row*128 + (col^((row&7)<<4));
// write side pre-swizzles per-lane global col (linear global_load_lds dest);
// read side same XOR: cs{0,1} = (quad*16 + {0,64}) ^ ((l16&7)<<4).
// Workspace: Xd bf16 [M*K] | Bt bf16 [N*K]  (160 MB).
// ---------------------------------------------------------------------------

typedef __attribute__((ext_vector_type(8))) short short8;   // 8 x bf16 frag
typedef __attribute__((ext_vector_type(4))) float f32x4;
typedef unsigned short ushort_t;
typedef __attribute__((address_space(3))) const char as3ch;

__device__ __forceinline__ float fp8_round_trip(float v) {
    int p = __builtin_amdgcn_cvt_pk_fp8_f32(v, v, 0, false);
    return __builtin_amdgcn_cvt_f32_fp8(p, 0);
}

__device__ __forceinline__ ushort_t f32_to_bf16(float f) {
    union { float f; unsigned u; } un; un.f = f;
    unsigned r = un.u + 0x7fffu + ((un.u >> 16) & 1u);
    return (ushort_t)(r >> 16);
}

// async 16B/lane global -> LDS (wave-uniform LDS base + lane*16)
__device__ __forceinline__ void async16(const void* g, void* l) {
    __builtin_amdgcn_global_load_lds(
        (const __attribute__((address_space(1))) unsigned int*)g,
        (__attribute__((address_space(3))) unsigned int*)l,
        16, 0, 0);
}

// ---------------------------------------------------------------------------
// quant_x v1: x[M,K] f32 -> Xd[M,K] bf16 (dequantized). One 128-elem fp8
// block per 32-lane half-wave; each lane handles one float4 (4 elems).
// ---------------------------------------------------------------------------
__global__ __launch_bounds__(256) void quant_x_kernel(
        const float* __restrict__ x, ushort_t* __restrict__ xd) {
    size_t tid  = (size_t)blockIdx.x * 256 + threadIdx.x;
    size_t base = tid * 4;
    float4 v = *(const float4*)(x + base);
    float amax = fmaxf(fmaxf(fabsf(v.x), fabsf(v.y)),
                       fmaxf(fabsf(v.z), fabsf(v.w)));
    #pragma unroll
    for (int m = 1; m < 32; m <<= 1)
        amax = fmaxf(amax, __shfl_xor(amax, m, 64));
    float scale = fmaxf(amax / 448.0f, 1e-12f);
    ushort4 o;
    o.x = f32_to_bf16(fp8_round_trip(v.x / scale) * scale);
    o.y = f32_to_bf16(fp8_round_trip(v.y / scale) * scale);
    o.z = f32_to_bf16(fp8_round_trip(v.z / scale) * scale);
    o.w = f32_to_bf16(fp8_round_trip(v.w / scale) * scale);
    *(ushort4*)(xd + base) = o;
}

// ---------------------------------------------------------------------------
// quant_w: w[K,N] f32 -> Bt[N,K] bf16 (dequantized + transposed). Unchanged.
// ---------------------------------------------------------------------------
__global__ __launch_bounds__(256) void quant_w_kernel(
        const float* __restrict__ w, ushort_t* __restrict__ bt,
        int K, int N) {
    __shared__ float lds[128 * 65];
    int k0 = blockIdx.x * 64;
    int n0 = blockIdx.y * 128;
    int t = threadIdx.x;
    int wid = t >> 6, lane = t & 63;
    int half = lane >> 5, l32 = lane & 31;

    #pragma unroll
    for (int rr = 0; rr < 8; ++rr) {
        int klocal = wid * 16 + rr * 2 + half;
        int k = k0 + klocal;
        float4 v = *(const float4*)(w + (size_t)k * N + n0 + l32 * 4);
        float amax = fmaxf(fmaxf(fabsf(v.x), fabsf(v.y)),
                           fmaxf(fabsf(v.z), fabsf(v.w)));
        #pragma unroll
        for (int m = 1; m < 32; m <<= 1)
            amax = fmaxf(amax, __shfl_xor(amax, m, 64));
        float scale = fmaxf(amax / 448.0f, 1e-12f);
        int nl = l32 * 4;
        lds[(nl + 0) * 65 + klocal] = fp8_round_trip(v.x / scale) * scale;
        lds[(nl + 1) * 65 + klocal] = fp8_round_trip(v.y / scale) * scale;
        lds[(nl + 2) * 65 + klocal] = fp8_round_trip(v.z / scale) * scale;
        lds[(nl + 3) * 65 + klocal] = fp8_round_trip(v.w / scale) * scale;
    }
    __syncthreads();
    #pragma unroll
    for (int it = 0; it < 8; ++it) {
        int idx = it * 256 + t;
        int j = idx >> 4;
        int c = idx & 15;
        const float* p = &lds[j * 65 + c * 4];
        ushort4 o;
        o.x = f32_to_bf16(p[0]);
        o.y = f32_to_bf16(p[1]);
        o.z = f32_to_bf16(p[2]);
        o.w = f32_to_bf16(p[3]);
        *(ushort4*)(bt + (size_t)(n0 + j) * K + k0 + c * 4) = o;
    }
}

// ---------------------------------------------------------------------------
// gemm256: C[M,N] = A[M,K](bf16) * Bt[N,K](bf16)^T + bias.
// 256x256 tile, BK=64, 512 threads = 8 waves (wr in {0,1} x wcn in {0..3});
// per-wave output 128x64 = acc[8][4] f32x4. LDS dbuf 128 KiB.
//
// Per-phase ladder (pinned asm ds_read order + in-order DS returns):
//  p1: issue [b01(4), a0 m0..m3 pairs(8)]; GBAR; WAITL(4) -> b+m0+m1 done
//      -> 8 MFMA; WAITL(0) -> m2+m3 -> 8 MFMA.
//  p2: issue a1(8); WAITL(4) -> m0,m1; WAITL(0) -> m2,m3.
//  p3: issue b23(4) [n0ks0,n0ks1,n1ks0,n1ks1]; WAITL(2) -> n0 col; WAITL(0).
//  p4: no reads; 16 MFMA from regs. p5-p8 mirror on buf1.
// Stage schedule (R3): p1: Bh1(T+1); p3: Ah0(T+2); p4: Ah1(T+2), WAITV(4);
// p5: Bh0(T+2); p6: Bh1(T+2); p7: Ah0(T+3); p8: Ah1+Bh0(T+3), WAITV(6).
// Ledger (loads): enter 6 [T+1 Ah0,Ah1,Bh0]; +2@p1 ->8; +2@p3 ->10; +2@p4
// ->12, WAITV(4) completes T+1 (+Ah0 T+2); +2@p5,+2@p6,+2@p7,+4@p8 ->14,
// WAITV(6) completes T+2; 6 remain = T+3's 3 halves. WAR: stages touch slots
// whose last ds_read is >= 1 barrier earlier (A-halves die p2/p6, B p3/p7).
// ---------------------------------------------------------------------------

#define GBAR()    asm volatile("s_barrier" ::: "memory")
#define WAITL(n)  asm volatile("s_waitcnt lgkmcnt(" #n ")" ::: "memory")
#define WAITV(n)  asm volatile("s_waitcnt vmcnt(" #n ")" ::: "memory")
#define SCHED0    __builtin_amdgcn_sched_barrier(0)
#define SETP(n)   __builtin_amdgcn_s_setprio(n)
#define MFMA16    __builtin_amdgcn_mfma_f32_16x16x32_bf16

#define DSR(dst, base, off) \
    asm volatile("ds_read_b128 %0, %1 offset:" #off : "=v"(dst) : "v"(base))

#define STAGE_A(h, kt, buf) do {                                             \
    const ushort_t* g_ = aSrc + (size_t)((h) * 128) * K + (size_t)(kt) * 64; \
    ushort_t* l_ = &sm[buf][0][(h) * 8192] + wid * 512;                      \
    async16(g_, l_);                                                         \
    async16(g_ + (size_t)64 * K, l_ + 4096);                                 \
} while (0)

#define STAGE_B(h, kt, buf) do {                                             \
    const ushort_t* g_ = bSrc + (size_t)((h) * 128) * K + (size_t)(kt) * 64; \
    ushort_t* l_ = &sm[buf][1][(h) * 8192] + wid * 512;                      \
    async16(g_, l_);                                                         \
    async16(g_ + (size_t)64 * K, l_ + 4096);                                 \
} while (0)

// LDS byte addresses (AS3): A tile at buf*65536, B tile at buf*65536+32768
#define PA(buf, hsel, cs) (lds3 + (buf) * 65536 + aBase + (hsel) * 8192 + (cs))
#define PB(buf, nsel, cs) (lds3 + (buf) * 65536 + 32768 + bBase + (nsel) * 4096 + (cs))

// issue order: n0ks0, n0ks1, n1ks0, n1ks1
#define ISSUE_B(buf, nsel) do {                                              \
    as3ch* p0_ = PB(buf, nsel, cs0); as3ch* p1_ = PB(buf, nsel, cs1);        \
    DSR(bb[0][0], p0_, 0);    DSR(bb[0][1], p1_, 0);                         \
    DSR(bb[1][0], p0_, 2048); DSR(bb[1][1], p1_, 2048);                      \
} while (0)

// issue order: m0ks0, m0ks1, m1ks0, m1ks1, m2..., m3...
#define ISSUE_A(dst, buf, hsel) do {                                         \
    as3ch* p0_ = PA(buf, hsel, cs0); as3ch* p1_ = PA(buf, hsel, cs1);        \
    DSR(dst[0][0], p0_, 0);    DSR(dst[0][1], p1_, 0);                       \
    DSR(dst[1][0], p0_, 2048); DSR(dst[1][1], p1_, 2048);                    \
    DSR(dst[2][0], p0_, 4096); DSR(dst[2][1], p1_, 4096);                    \
    DSR(dst[3][0], p0_, 6144); DSR(dst[3][1], p1_, 6144);                    \
} while (0)

// one m-row of a quadrant: 4 MFMA (2 n-cols x 2 k-slices), 2 indep chains
#define MFMA_M(AS, mm, mb, nb) do {                                          \
    acc[(mb)+(mm)][(nb)  ] = MFMA16(AS[mm][0], bb[0][0], acc[(mb)+(mm)][(nb)  ], 0,0,0); \
    acc[(mb)+(mm)][(nb)+1] = MFMA16(AS[mm][0], bb[1][0], acc[(mb)+(mm)][(nb)+1], 0,0,0); \
    acc[(mb)+(mm)][(nb)  ] = MFMA16(AS[mm][1], bb[0][1], acc[(mb)+(mm)][(nb)  ], 0,0,0); \
    acc[(mb)+(mm)][(nb)+1] = MFMA16(AS[mm][1], bb[1][1], acc[(mb)+(mm)][(nb)+1], 0,0,0); \
} while (0)

// one n-col of a quadrant: 8 MFMA (4 m-rows x 2 k-slices), 4 indep chains
#define MFMA_N(AS, n_, mb, nb) do {                                          \
    _Pragma("unroll") for (int mm_ = 0; mm_ < 4; ++mm_) {                    \
        acc[(mb)+mm_][(nb)+(n_)] = MFMA16(AS[mm_][0], bb[n_][0], acc[(mb)+mm_][(nb)+(n_)], 0,0,0); \
        acc[(mb)+mm_][(nb)+(n_)] = MFMA16(AS[mm_][1], bb[n_][1], acc[(mb)+mm_][(nb)+(n_)], 0,0,0); \
    }                                                                        \
} while (0)

__global__ __launch_bounds__(512, 2) void gemm256_kernel(
        const ushort_t* __restrict__ A, const ushort_t* __restrict__ B,
        const float* __restrict__ bias, float* __restrict__ C,
        int M, int N, int K) {
    __shared__ ushort_t sm[2][2][16384];   // 128 KiB

    const int t = threadIdx.x;
    const int wid = t >> 6;
    const int lane = t & 63;
    const int quad = lane >> 4, l16 = lane & 15;
    const int wr = wid >> 2, wcn = wid & 3;

    // T1: XCD-aware swizzle on flattened block id (nwg = 1024, % 8 == 0)
    const int nwg = gridDim.x;
    const int bid = blockIdx.x;
    int wg = bid;
    if ((nwg & 7) == 0) { const int cpx = nwg >> 3; wg = (bid & 7) * cpx + (bid >> 3); }
    const int nbn = N >> 8;
    const int bm = wg / nbn, bn = wg % nbn;

    // staging: thread t covers LDS linear byte t*16 per 64-row statement:
    // row = t>>3, col = (t&7)*16. Pre-swizzled global col = col ^ ((row&7)<<4).
    const int srow = t >> 3;
    const int scol = ((((t & 7) * 16) ^ (((t >> 3) & 7) << 4)) >> 1); // ushorts
    const ushort_t* aSrc = A + (size_t)(bm * 256 + srow) * K + scol;
    const ushort_t* bSrc = B + (size_t)(bn * 256 + srow) * K + scol;

    // ds_read addressing: row base l16*128; k-slice cols XOR-swizzled by row
    const int xr4 = (l16 & 7) << 4;
    const int cs0 = (quad * 16) ^ xr4;
    const int cs1 = (quad * 16 + 64) ^ xr4;
    const int aBase = wr * 16384 + l16 * 128;    // bytes within A tile
    const int bBase = wcn * 8192 + l16 * 128;    // bytes within B tile
    as3ch* lds3 = (as3ch*)sm;

    f32x4 acc[8][4] = {};
    short8 a0[4][2], a1[4][2], bb[2][2];

    const int NT = K >> 6;     // K-tiles (64)
    const int NI = NT >> 1;    // iterations (32)

    // prologue: tile0 (4 halves) + tile1 Ah0,Ah1,Bh0 = 14 loads; drain tile0
    STAGE_A(0, 0, 0); STAGE_A(1, 0, 0); STAGE_B(0, 0, 0); STAGE_B(1, 0, 0);
    STAGE_A(0, 1, 1); STAGE_A(1, 1, 1); STAGE_B(0, 1, 1);
    WAITV(6); GBAR();

    for (int i = 0; i < NI; ++i) {
        const int T  = 2 * i;
        const int t1 = T + 1;
        const int t2 = (T + 2 < NT) ? T + 2 : 0;   // clamped: re-stages tile0,
        const int t3 = (T + 3 < NT) ? T + 3 : 0;   // never computed

        // ---- phase 1: Q0 = a0 x b01 (tile T, buf0)
        ISSUE_B(0, 0); ISSUE_A(a0, 0, 0);
        STAGE_B(1, t1, 1);
        GBAR();
        WAITL(4); SCHED0; SETP(1);
        MFMA_M(a0, 0, 0, 0); MFMA_M(a0, 1, 0, 0);
        WAITL(0); SCHED0;
        MFMA_M(a0, 2, 0, 0); MFMA_M(a0, 3, 0, 0);
        SETP(0); GBAR();
        // ---- phase 2: Q1 = a1 x b01
        ISSUE_A(a1, 0, 1);
        GBAR();
        WAITL(4); SCHED0; SETP(1);
        MFMA_M(a1, 0, 4, 0); MFMA_M(a1, 1, 4, 0);
        WAITL(0); SCHED0;
        MFMA_M(a1, 2, 4, 0); MFMA_M(a1, 3, 4, 0);
        SETP(0); GBAR();
        // ---- phase 3: Q2 = a0 x b23
        ISSUE_B(0, 1);
        STAGE_A(0, t2, 0);
        GBAR();
        WAITL(2); SCHED0; SETP(1);
        MFMA_N(a0, 0, 0, 2);
        WAITL(0); SCHED0;
        MFMA_N(a0, 1, 0, 2);
        SETP(0); GBAR();
        // ---- phase 4: Q3 = a1 x b23 (all regs)
        STAGE_A(1, t2, 0);
        WAITV(4);
        GBAR(); SETP(1);
        MFMA_N(a1, 0, 4, 2); MFMA_N(a1, 1, 4, 2);
        SETP(0); GBAR();
        // ---- phase 5: Q0 (tile T+1, buf1)
        ISSUE_B(1, 0); ISSUE_A(a0, 1, 0);
        STAGE_B(0, t2, 0);
        GBAR();
        WAITL(4); SCHED0; SETP(1);
        MFMA_M(a0, 0, 0, 0); MFMA_M(a0, 1, 0, 0);
        WAITL(0); SCHED0;
        MFMA_M(a0, 2, 0, 0); MFMA_M(a0, 3, 0, 0);
        SETP(0); GBAR();
        // ---- phase 6: Q1
        ISSUE_A(a1, 1, 1);
        STAGE_B(1, t2, 0);
        GBAR();
        WAITL(4); SCHED0; SETP(1);
        MFMA_M(a1, 0, 4, 0); MFMA_M(a1, 1, 4, 0);
        WAITL(0); SCHED0;
        MFMA_M(a1, 2, 4, 0); MFMA_M(a1, 3, 4, 0);
        SETP(0); GBAR();
        // ---- phase 7: Q2
        ISSUE_B(1, 1);
        STAGE_A(0, t3, 1);
        GBAR();
        WAITL(2); SCHED0; SETP(1);
        MFMA_N(a0, 0, 0, 2);
        WAITL(0); SCHED0;
        MFMA_N(a0, 1, 0, 2);
        SETP(0); GBAR();
        // ---- phase 8: Q3
        STAGE_A(1, t3, 1);
        STAGE_B(0, t3, 1);
        WAITV(6);
        GBAR(); SETP(1);
        MFMA_N(a1, 0, 4, 2); MFMA_N(a1, 1, 4, 2);
        SETP(0); GBAR();
    }

    // epilogue: C/D layout col = lane&15, row = quad*4 + reg (m89/m91)
    #pragma unroll
    for (int nt = 0; nt < 4; ++nt) {
        const int col = bn * 256 + wcn * 64 + nt * 16 + l16;
        const float bv = bias[col];
        #pragma unroll
        for (int mt = 0; mt < 8; ++mt) {
            const int row0 = bm * 256 + wr * 128 + mt * 16 + quad * 4;
            #pragma unroll
            for (int r = 0; r < 4; ++r)
                C[(size_t)(row0 + r) * N + col] = acc[mt][nt][r] + bv;
        }
    }
}

// ---------------------------------------------------------------------------
extern "C" void kernel_launch(void* const* d_in, const int* in_sizes, int n_in,
                              void* d_out, int out_size, void* d_ws, size_t ws_size,
                              hipStream_t stream) {
    const float* x    = (const float*)d_in[0];
    const float* w    = (const float*)d_in[1];
    const float* bias = (const float*)d_in[2];
    float* out = (float*)d_out;

    const int N = in_sizes[2];              // 4096
    const int K = in_sizes[1] / N;          // 4096
    const int M = in_sizes[0] / K;          // 16384

    ushort_t* xd = (ushort_t*)d_ws;                  // M*K bf16
    ushort_t* bt = xd + (size_t)M * K;               // N*K bf16
    // requires ws_size >= (M*K + N*K)*2 = 160 MB

    quant_x_kernel<<<(size_t)M * K / 1024, 256, 0, stream>>>(x, xd);
    quant_w_kernel<<<dim3(K / 64, N / 128), 256, 0, stream>>>(w, bt, K, N);
    gemm256_kernel<<<dim3((M / 256) * (N / 256)), 512, 0, stream>>>(
        xd, bt, bias, out, M, N, K);
}